// Round 1
// baseline (850.471 us; speedup 1.0000x reference)
//
#include <hip/hip_runtime.h>
#include <math.h>

#define H 4096
#define TWO_H 8192
#define FIVE_H 20480
#define EPS 1e-5f

// ---------------------------------------------------------------------------
// Kernel 1: z[row] = dot(W[row, :], concat(h0, h1)) for row in [0, 5H)
// 4 rows per block; x (concat(h0,h1), 8192 floats) held in registers,
// reused across the 4 rows. W reads are float4-coalesced per row.
// ---------------------------------------------------------------------------
__global__ __launch_bounds__(256) void matvec_kernel(
    const float* __restrict__ W, const float* __restrict__ h0,
    const float* __restrict__ h1, float* __restrict__ z) {
  const int row0 = blockIdx.x * 4;
  const int tid = threadIdx.x;

  // Load x into registers: 8 float4 per thread (32 floats).
  // float4 index for iteration j: j*256 + tid. j<4 -> h0 half, j>=4 -> h1.
  float4 xv[8];
  const float4* x0 = (const float4*)h0;
  const float4* x1 = (const float4*)h1;
#pragma unroll
  for (int j = 0; j < 4; ++j) xv[j] = x0[j * 256 + tid];
#pragma unroll
  for (int j = 0; j < 4; ++j) xv[4 + j] = x1[j * 256 + tid];

  float acc[4] = {0.f, 0.f, 0.f, 0.f};
#pragma unroll
  for (int r = 0; r < 4; ++r) {
    const float4* Wrow = (const float4*)(W + (size_t)(row0 + r) * TWO_H);
#pragma unroll
    for (int j = 0; j < 8; ++j) {
      float4 w = Wrow[j * 256 + tid];
      acc[r] += w.x * xv[j].x + w.y * xv[j].y + w.z * xv[j].z + w.w * xv[j].w;
    }
  }

  // Reduce the 4 accumulators across the block (256 threads = 4 waves).
  __shared__ float red[4][4];  // [wave][row]
  const int lane = tid & 63;
  const int wv = tid >> 6;
#pragma unroll
  for (int r = 0; r < 4; ++r) {
    float a = acc[r];
#pragma unroll
    for (int off = 32; off; off >>= 1) a += __shfl_down(a, off, 64);
    if (lane == 0) red[wv][r] = a;
  }
  __syncthreads();
  if (tid < 4) {
    z[row0 + tid] = red[0][tid] + red[1][tid] + red[2][tid] + red[3][tid];
  }
}

// ---------------------------------------------------------------------------
// Kernel 2: all LayerNorms + gates + cell update. Single block, 1024 threads,
// each thread owns 4 elements (e = tid + j*1024).
// ---------------------------------------------------------------------------
__device__ __forceinline__ float block_sum_1024(float v, float* sred) {
#pragma unroll
  for (int off = 32; off; off >>= 1) v += __shfl_down(v, off, 64);
  const int lane = threadIdx.x & 63;
  const int wv = threadIdx.x >> 6;
  __syncthreads();  // protect sred against reuse from a previous call
  if (lane == 0) sred[wv] = v;
  __syncthreads();
  float s = 0.f;
#pragma unroll
  for (int w = 0; w < 16; ++w) s += sred[w];  // LDS broadcast reads
  return s;
}

__global__ __launch_bounds__(1024) void epilogue_kernel(
    const float* __restrict__ z, const float* __restrict__ c0,
    const float* __restrict__ c1, const float* __restrict__ ffio_g,
    const float* __restrict__ ffio_b, const float* __restrict__ u_g,
    const float* __restrict__ u_b, const float* __restrict__ c_g,
    const float* __restrict__ c_b, float* __restrict__ out) {
  const int tid = threadIdx.x;
  __shared__ float sred[16];

  // Load the 5 z-parts: zp[p][j] = z[p*H + tid + j*1024]
  float zp[5][4];
#pragma unroll
  for (int p = 0; p < 5; ++p)
#pragma unroll
    for (int j = 0; j < 4; ++j) zp[p][j] = z[p * H + j * 1024 + tid];

  // Per-part mean / rstd (jnp.var == E[x^2] - E[x]^2 over the H dim)
  float mean[5], rstd[5];
#pragma unroll
  for (int p = 0; p < 5; ++p) {
    float s = zp[p][0] + zp[p][1] + zp[p][2] + zp[p][3];
    float q = zp[p][0] * zp[p][0] + zp[p][1] * zp[p][1] +
              zp[p][2] * zp[p][2] + zp[p][3] * zp[p][3];
    s = block_sum_1024(s, sred);
    q = block_sum_1024(q, sred);
    float m = s * (1.0f / H);
    float v = q * (1.0f / H) - m * m;
    mean[p] = m;
    rstd[p] = rsqrtf(v + EPS);
  }

  // Gates + pre-LN cell
  float oo[4], cpre[4];
#pragma unroll
  for (int j = 0; j < 4; ++j) {
    const int e = tid + j * 1024;
    float n0 = (zp[0][j] - mean[0]) * rstd[0] * ffio_g[0 * H + e] + ffio_b[0 * H + e];
    float n1 = (zp[1][j] - mean[1]) * rstd[1] * ffio_g[1 * H + e] + ffio_b[1 * H + e];
    float n2 = (zp[2][j] - mean[2]) * rstd[2] * ffio_g[2 * H + e] + ffio_b[2 * H + e];
    float n3 = (zp[3][j] - mean[3]) * rstd[3] * ffio_g[3 * H + e] + ffio_b[3 * H + e];
    float n4 = (zp[4][j] - mean[4]) * rstd[4] * u_g[e] + u_b[e];
    float f0 = 1.f / (1.f + expf(-n0));
    float f1 = 1.f / (1.f + expf(-n1));
    float ig = 1.f / (1.f + expf(-n2));
    oo[j]    = 1.f / (1.f + expf(-n3));
    float uu = tanhf(n4);
    cpre[j] = ig * uu + f0 * c0[e] + f1 * c1[e];
  }

  // LayerNorm over the new cell
  {
    float s = cpre[0] + cpre[1] + cpre[2] + cpre[3];
    float q = cpre[0] * cpre[0] + cpre[1] * cpre[1] + cpre[2] * cpre[2] +
              cpre[3] * cpre[3];
    s = block_sum_1024(s, sred);
    q = block_sum_1024(q, sred);
    float m = s * (1.0f / H);
    float v = q * (1.0f / H) - m * m;
    float r = rsqrtf(v + EPS);
#pragma unroll
    for (int j = 0; j < 4; ++j) {
      const int e = tid + j * 1024;
      float ncell = (cpre[j] - m) * r * c_g[e] + c_b[e];
      out[H + e] = ncell;             // new_cell
      out[e] = oo[j] * tanhf(ncell);  // new_hidden
    }
  }
}

extern "C" void kernel_launch(void* const* d_in, const int* in_sizes, int n_in,
                              void* d_out, int out_size, void* d_ws,
                              size_t ws_size, hipStream_t stream) {
  const float* h0 = (const float*)d_in[0];
  const float* c0 = (const float*)d_in[1];
  const float* h1 = (const float*)d_in[2];
  const float* c1 = (const float*)d_in[3];
  const float* W = (const float*)d_in[4];
  const float* ffio_g = (const float*)d_in[5];
  const float* ffio_b = (const float*)d_in[6];
  const float* u_g = (const float*)d_in[7];
  const float* u_b = (const float*)d_in[8];
  const float* c_g = (const float*)d_in[9];
  const float* c_b = (const float*)d_in[10];
  float* out = (float*)d_out;
  float* z = (float*)d_ws;  // 5H floats = 80 KiB scratch

  matvec_kernel<<<FIVE_H / 4, 256, 0, stream>>>(W, h0, h1, z);
  epilogue_kernel<<<1, 1024, 0, stream>>>(z, c0, c1, ffio_g, ffio_b, u_g, u_b,
                                          c_g, c_b, out);
}